// Round 10
// baseline (215.589 us; speedup 1.0000x reference)
//
#include <hip/hip_runtime.h>
#include <hip/hip_bf16.h>

#define T_ALL 512
#define TB 16
#define NB (T_ALL / TB)
#define LOG2E 1.44269504088896f
#define XSTR 68   // padded xg row stride (floats)

typedef __attribute__((ext_vector_type(8))) short bf16x8;
typedef __attribute__((ext_vector_type(4))) float f32x4;

#define DPPF(v, CTRL) __uint_as_float((unsigned)__builtin_amdgcn_update_dpp(0, (int)__float_as_uint(v), (CTRL), 0xF, 0xF, true))
#define SWZF(v, PAT)  __uint_as_float((unsigned)__builtin_amdgcn_ds_swizzle((int)__float_as_uint(v), (PAT)))
#define BPERM(a, v)   __uint_as_float((unsigned)__builtin_amdgcn_ds_bpermute((a), (int)__float_as_uint(v)))

// fast f32->bf16 pair pack: +0x8000 (round-to-nearest, ties up) + v_perm_b32
__device__ __forceinline__ unsigned pack2fast(float a, float b) {
    const unsigned ua = __float_as_uint(a) + 0x8000u;
    const unsigned ub = __float_as_uint(b) + 0x8000u;
    return __builtin_amdgcn_perm(ub, ua, 0x07060302u);  // {b_hi16, a_hi16}
}
__device__ __forceinline__ bf16x8 make_frag(float4 lo, float4 hi) {
    union { unsigned u[4]; bf16x8 v; } r;
    r.u[0] = pack2fast(lo.x, lo.y);
    r.u[1] = pack2fast(lo.z, lo.w);
    r.u[2] = pack2fast(hi.x, hi.y);
    r.u[3] = pack2fast(hi.z, hi.w);
    return r.v;
}
__device__ __forceinline__ float4 scale4(float4 v, float s) {
    return make_float4(v.x * s, v.y * s, v.z * s, v.w * s);
}
__device__ __forceinline__ float4 relu4(float4 v) {
    return make_float4(fmaxf(v.x, 0.f), fmaxf(v.y, 0.f), fmaxf(v.z, 0.f), fmaxf(v.w, 0.f));
}
__device__ __forceinline__ float2 pkfma(float2 a, float2 b, float2 c) {
    return make_float2(fmaf(a.x, b.x, c.x), fmaf(a.y, b.y, c.y));
}
__device__ __forceinline__ float2 pkmul(float2 a, float2 b) {
    return make_float2(a.x * b.x, a.y * b.y);
}
__device__ __forceinline__ float tanh_c(float c) {
    return fmaf(2.0f, __builtin_amdgcn_rcpf(
        1.0f + __builtin_amdgcn_exp2f(-2.0f * LOG2E * c)), -1.0f);
}
__device__ __forceinline__ float fsigm(float x) {
    return __builtin_amdgcn_rcpf(1.0f + __builtin_amdgcn_exp2f(-LOG2E * x));
}

// Three-wave specialization: 1 row per 192-thread block, 2048 blocks
// (= 6144 waves = 6 waves/SIMD; v9 had 4).
// Wave0: LSTM1 recurrence. Butterfly dot (rows T,T^2,T^1,T^3 pre-permuted,
//   pair-packed) + 2 DPP xor-adds; h1(t-1) gathered via ONE broadcast
//   ds_read_b128 from the h1 ring (replaces v9's 4 ds_bpermute).
// Wave1: LSTM2 scan of chunk c-1 (gates2 via one K-padded MFMA into xg2l,
//   per-step Whh2 quad-reduce + swizzle combine) + final FC/sigmoid/store.
// Wave2: x global prefetch + MFMA xg staging for chunk c+1 (double-buffered).
__global__ __launch_bounds__(192, 6)
void lstm_fused_v10(const float* __restrict__ x,
        const float* __restrict__ Wih1, const float* __restrict__ Whh1,
        const float* __restrict__ bih1, const float* __restrict__ bhh1,
        const float* __restrict__ Wih2, const float* __restrict__ Whh2,
        const float* __restrict__ bih2, const float* __restrict__ bhh2,
        const float* __restrict__ Wfc,  const float* __restrict__ bfc,
        float* __restrict__ out)
{
    __shared__ __align__(16) float xgl[2][TB * XSTR];   // xg double buffer
    __shared__ __align__(16) float h1l[2][TB][16];      // h1 chunk ring
    __shared__ __align__(16) float xg2l[TB * 16];       // LSTM2 gate preacts

    const int tid = threadIdx.x;
    const int wid = tid >> 6;
    const int lane = tid & 63;
    const size_t b = blockIdx.x;

    const int tl = lane & 15;     // MFMA: A row / B,C col
    const int kh = lane >> 4;     // MFMA: k-group
    const int T1 = lane & 3;      // LSTM1 gate type AND k-slice
    const int j1 = lane >> 2;     // LSTM1 h-unit

    const float aA1 = (T1 == 2) ? 2.0f : 1.0f, aB1 = (T1 == 2) ? -1.0f : 0.0f;

    // ---- MFMA B-frags: Wih1^T pre-scaled per gate block (wave2 staging) ----
    bf16x8 wb[4][2];
    float bias1[4];
#pragma unroll
    for (int n = 0; n < 4; ++n) {
        const float scn = (n == 2) ? 2.0f * LOG2E : LOG2E;
#pragma unroll
        for (int kk = 0; kk < 2; ++kk) {
            const float* wp = Wih1 + (size_t)(n * 16 + tl) * 64 + kk * 32 + kh * 8;
            wb[n][kk] = make_frag(scale4(*(const float4*)wp, scn),
                                  scale4(*(const float4*)(wp + 4), scn));
        }
        bias1[n] = (bih1[n * 16 + tl] + bhh1[n * 16 + tl]) * scn;
    }

    // ---- LSTM1 butterfly weights, pair-packed (wave0) ----
    float2 wrA0, wrA1, wrB0, wrB1, wrC0, wrC1, wrD0, wrD1;
    {
        const float sA = (T1 == 2) ? 2.0f * LOG2E : LOG2E;
        const float sB = ((T1 ^ 2) == 2) ? 2.0f * LOG2E : LOG2E;
        const float sC = ((T1 ^ 1) == 2) ? 2.0f * LOG2E : LOG2E;
        const float sD = ((T1 ^ 3) == 2) ? 2.0f * LOG2E : LOG2E;
        const float4 wa  = scale4(*(const float4*)(Whh1 + ((T1    ) * 16 + j1) * 16 + 4 * T1), sA);
        const float4 wbv = scale4(*(const float4*)(Whh1 + ((T1 ^ 2) * 16 + j1) * 16 + 4 * T1), sB);
        const float4 wc  = scale4(*(const float4*)(Whh1 + ((T1 ^ 1) * 16 + j1) * 16 + 4 * T1), sC);
        const float4 wd  = scale4(*(const float4*)(Whh1 + ((T1 ^ 3) * 16 + j1) * 16 + 4 * T1), sD);
        wrA0 = make_float2(wa.x, wa.y);   wrA1 = make_float2(wa.z, wa.w);
        wrB0 = make_float2(wbv.x, wbv.y); wrB1 = make_float2(wbv.z, wbv.w);
        wrC0 = make_float2(wc.x, wc.y);   wrC1 = make_float2(wc.z, wc.w);
        wrD0 = make_float2(wd.x, wd.y);   wrD1 = make_float2(wd.z, wd.w);
    }

    // ---- gates2 MFMA operands (wave1): A = Wih2 row tl, K zero-padded ----
    bf16x8 wA2;
    {
        union { unsigned u[4]; bf16x8 v; } z;
        z.u[0] = z.u[1] = z.u[2] = z.u[3] = 0u;
        wA2 = z.v;
        if (kh < 2) {
            const float scr = ((tl >> 2) == 2) ? 2.0f * LOG2E : LOG2E;
            const float* wp = Wih2 + tl * 16 + kh * 8;
            wA2 = make_frag(scale4(*(const float4*)wp, scr),
                            scale4(*(const float4*)(wp + 4), scr));
        }
    }
    f32x4 bias2v;
#pragma unroll
    for (int r = 0; r < 4; ++r) {
        const int g = 4 * kh + r;
        bias2v[r] = (bih2[g] + bhh2[g]) * (((g >> 2) == 2) ? 2.0f * LOG2E : LOG2E);
    }

    // ---- LSTM2 per-step weights (wave1): lane = 16*m2 + 4*T2 + s2 ----
    const int m2 = lane >> 4;
    const int T2 = (lane >> 2) & 3;
    const int s2 = lane & 3;
    const int row2 = T2 * 4 + m2;
    const float sc2 = (T2 == 2) ? 2.0f * LOG2E : LOG2E;
    const float aA2 = (T2 == 2) ? 2.0f : 1.0f, aB2 = (T2 == 2) ? -1.0f : 0.0f;
    const float w2h = Whh2[row2 * 4 + s2] * sc2;
    const float4 wfc = *(const float4*)(Wfc + lane * 4);
    const float bfcv = bfc[lane];

    const int ahs = s2 << 6;               // h2[s] from lane 16s
    const int gidx = T1 * 16 + j1;         // wave0's gate column in xg

    float c1r = 0.f, h1r = 0.f;            // wave0 state (valid on lanes 4j)
    float c2r = 0.f, h2v = 0.f, h2s = 0.f; // wave1 LSTM2 state

    const float* xb = x + b * (size_t)(T_ALL * 64);
    float4 xpf[4];

#define LOADX(CH) do { \
    const float* _src = xb + (size_t)(CH) * (TB * 64); \
    _Pragma("unroll") \
    for (int _kk = 0; _kk < 2; ++_kk) \
        _Pragma("unroll") \
        for (int _hf = 0; _hf < 2; ++_hf) \
            xpf[_kk * 2 + _hf] = *(const float4*)(_src + tl * 64 + _kk * 32 + kh * 8 + _hf * 4); \
} while (0)

#define MFMA_XG(BUF) do { \
    bf16x8 _a0 = make_frag(xpf[0], xpf[1]); \
    bf16x8 _a1 = make_frag(xpf[2], xpf[3]); \
    _Pragma("unroll") \
    for (int _n = 0; _n < 4; ++_n) { \
        f32x4 _acc = {bias1[_n], bias1[_n], bias1[_n], bias1[_n]}; \
        _acc = __builtin_amdgcn_mfma_f32_16x16x32_bf16(_a0, wb[_n][0], _acc, 0, 0, 0); \
        _acc = __builtin_amdgcn_mfma_f32_16x16x32_bf16(_a1, wb[_n][1], _acc, 0, 0, 0); \
        _Pragma("unroll") \
        for (int _r = 0; _r < 4; ++_r) \
            xgl[BUF][(kh * 4 + _r) * XSTR + _n * 16 + tl] = _acc[_r]; \
    } \
} while (0)

// LSTM1 step: h(t-1) via one broadcast ds_read_b128 from h1 ring (HP)
#define STEP1(XU, HP) do { \
    const float4 _gq = *(const float4*)((HP) + 4 * T1); \
    const float2 _g01 = make_float2(_gq.x, _gq.y); \
    const float2 _g23 = make_float2(_gq.z, _gq.w); \
    float2 _aA = pkmul(wrA0, _g01); _aA = pkfma(wrA1, _g23, _aA); \
    float2 _aB = pkmul(wrB0, _g01); _aB = pkfma(wrB1, _g23, _aB); \
    float2 _aC = pkmul(wrC0, _g01); _aC = pkfma(wrC1, _g23, _aC); \
    float2 _aD = pkmul(wrD0, _g01); _aD = pkfma(wrD1, _g23, _aD); \
    const float _sA = _aA.x + _aA.y, _sB2 = _aB.x + _aB.y; \
    const float _sC = _aC.x + _aC.y, _sD = _aD.x + _aD.y; \
    const float _u0 = _sA + DPPF(_sC, 0xB1); \
    const float _u1 = _sB2 + DPPF(_sD, 0xB1); \
    const float _pre = _u0 + DPPF(_u1, 0x4E) + (XU); \
    const float _s1 = __builtin_amdgcn_rcpf(1.0f + __builtin_amdgcn_exp2f(-_pre)); \
    const float _act = fmaf(aA1, _s1, aB1); \
    const float _fv = DPPF(_act, 0x55); \
    const float _gv = DPPF(_act, 0xAA); \
    const float _ov = DPPF(_act, 0xFF); \
    c1r = fmaf(_fv, c1r, _act * _gv);        /* valid on T1==0 (act = i there) */ \
    h1r = _ov * tanh_c(c1r);                 /* valid on T1==0 */ \
} while (0)

#define GATES2(RG) do { \
    bf16x8 _bf; \
    { union { unsigned u[4]; bf16x8 v; } _z; _z.u[0]=_z.u[1]=_z.u[2]=_z.u[3]=0u; _bf = _z.v; } \
    if (kh < 2) { \
        const float4 _h0 = *(const float4*)&h1l[RG][tl][8 * kh]; \
        const float4 _h1 = *(const float4*)&h1l[RG][tl][8 * kh + 4]; \
        _bf = make_frag(relu4(_h0), relu4(_h1)); \
    } \
    f32x4 _acc = bias2v; \
    _acc = __builtin_amdgcn_mfma_f32_16x16x32_bf16(wA2, _bf, _acc, 0, 0, 0); \
    _Pragma("unroll") \
    for (int _r = 0; _r < 4; ++_r) \
        xg2l[tl * 16 + 4 * kh + _r] = _acc[_r]; \
} while (0)

#define LSTM2_STEP(TT) do { \
    const float _xg2 = xg2l[(TT) * 16 + row2]; \
    float _p2 = w2h * h2s; \
    _p2 += DPPF(_p2, 0xB1); \
    _p2 += DPPF(_p2, 0x4E); \
    _p2 += _xg2; \
    const float _act2 = fmaf(aA2, \
        __builtin_amdgcn_rcpf(1.0f + __builtin_amdgcn_exp2f(-_p2)), aB2); \
    const float _fv2 = SWZF(_act2, 0x101F); \
    const float _gv2 = SWZF(_act2, 0x201F); \
    const float _ov2 = SWZF(_act2, 0x301F); \
    c2r = fmaf(_fv2, c2r, _act2 * _gv2);     /* valid on T2==0 */ \
    h2v = _ov2 * tanh_c(c2r); \
    h2s = BPERM(ahs, h2v); \
} while (0)

    // ---- pre-loop: wave2 stages chunk0's xg + prefetch chunk1; wave0 zeroes
    //      the h(-1) slot the first gather reads ----
    if (wid == 2) {
        LOADX(0);
        MFMA_XG(0);
        LOADX(1);
    }
    if (wid == 0 && T1 == 0) h1l[1][15][j1] = 0.f;   // h(-1) = 0
    __syncthreads();

    for (int c = 0; c < NB; ++c) {
        if (wid == 0) {
            const float* xrow = &xgl[c & 1][0];
            const int rg = c & 1;
            const float* hprev0 = &h1l[rg ^ 1][15][0];
#pragma unroll
            for (int tt = 0; tt < TB; ++tt) {
                const float* hp = (tt == 0) ? hprev0 : &h1l[rg][tt - 1][0];
                STEP1(xrow[tt * XSTR + gidx], hp);
                if (T1 == 0) h1l[rg][tt][j1] = h1r;
            }
        } else if (wid == 1) {
            if (c >= 1) {
                GATES2((c - 1) & 1);
#pragma unroll
                for (int tt = 0; tt < TB; ++tt)
                    LSTM2_STEP(tt);
            }
        } else {
            if (c + 1 < NB) {
                bf16x8 a0s = make_frag(xpf[0], xpf[1]);
                bf16x8 a1s = make_frag(xpf[2], xpf[3]);
                if (c + 2 < NB) LOADX(c + 2);
#pragma unroll
                for (int n = 0; n < 4; ++n) {
                    f32x4 acc = {bias1[n], bias1[n], bias1[n], bias1[n]};
                    acc = __builtin_amdgcn_mfma_f32_16x16x32_bf16(a0s, wb[n][0], acc, 0, 0, 0);
                    acc = __builtin_amdgcn_mfma_f32_16x16x32_bf16(a1s, wb[n][1], acc, 0, 0, 0);
#pragma unroll
                    for (int r = 0; r < 4; ++r)
                        xgl[(c + 1) & 1][(kh * 4 + r) * XSTR + n * 16 + tl] = acc[r];
                }
            }
        }
        __syncthreads();
    }

    // ---- tail: wave1 finishes LSTM2 chunk NB-1, then FC + sigmoid ----
    if (wid == 1) {
        GATES2((NB - 1) & 1);
#pragma unroll
        for (int tt = 0; tt < TB; ++tt)
            LSTM2_STEP(tt);

        const float hq0 = __shfl(h2v, 0);    // h2[m] valid on lanes 16m (T2==0)
        const float hq1 = __shfl(h2v, 16);
        const float hq2 = __shfl(h2v, 32);
        const float hq3 = __shfl(h2v, 48);
        float accf = bfcv;
        accf = fmaf(wfc.x, hq0, accf);
        accf = fmaf(wfc.y, hq1, accf);
        accf = fmaf(wfc.z, hq2, accf);
        accf = fmaf(wfc.w, hq3, accf);
        out[b * 64 + lane] = fsigm(accf);
    }
#undef LOADX
#undef MFMA_XG
#undef STEP1
#undef GATES2
#undef LSTM2_STEP
}

extern "C" void kernel_launch(void* const* d_in, const int* in_sizes, int n_in,
                              void* d_out, int out_size, void* d_ws, size_t ws_size,
                              hipStream_t stream) {
    const float* x    = (const float*)d_in[0];
    const float* Wih1 = (const float*)d_in[1];
    const float* Whh1 = (const float*)d_in[2];
    const float* bih1 = (const float*)d_in[3];
    const float* bhh1 = (const float*)d_in[4];
    const float* Wih2 = (const float*)d_in[5];
    const float* Whh2 = (const float*)d_in[6];
    const float* bih2 = (const float*)d_in[7];
    const float* bhh2 = (const float*)d_in[8];
    const float* Wfc  = (const float*)d_in[9];
    const float* bfc  = (const float*)d_in[10];
    float* out = (float*)d_out;

    lstm_fused_v10<<<dim3(2048), dim3(192), 0, stream>>>(
        x, Wih1, Whh1, bih1, bhh1, Wih2, Whh2, bih2, bhh2, Wfc, bfc, out);
}

// Round 11
// 140.142 us; speedup vs baseline: 1.5384x; 1.5384x over previous
//
#include <hip/hip_runtime.h>
#include <hip/hip_bf16.h>

#define T_ALL 512
#define TB 16
#define NB (T_ALL / TB)
#define LOG2E 1.44269504088896f
#define XSTR 68   // padded xg row stride (floats)

typedef __attribute__((ext_vector_type(8))) short bf16x8;
typedef __attribute__((ext_vector_type(4))) float f32x4;

#define DPPF(v, CTRL) __uint_as_float((unsigned)__builtin_amdgcn_update_dpp(0, (int)__float_as_uint(v), (CTRL), 0xF, 0xF, true))
#define SWZF(v, PAT)  __uint_as_float((unsigned)__builtin_amdgcn_ds_swizzle((int)__float_as_uint(v), (PAT)))
#define BPERM(a, v)   __uint_as_float((unsigned)__builtin_amdgcn_ds_bpermute((a), (int)__float_as_uint(v)))

// fast f32->bf16 pair pack: +0x8000 (round-to-nearest, ties up) + v_perm_b32
__device__ __forceinline__ unsigned pack2fast(float a, float b) {
    const unsigned ua = __float_as_uint(a) + 0x8000u;
    const unsigned ub = __float_as_uint(b) + 0x8000u;
    return __builtin_amdgcn_perm(ub, ua, 0x07060302u);  // {b_hi16, a_hi16}
}
__device__ __forceinline__ bf16x8 make_frag(float4 lo, float4 hi) {
    union { unsigned u[4]; bf16x8 v; } r;
    r.u[0] = pack2fast(lo.x, lo.y);
    r.u[1] = pack2fast(lo.z, lo.w);
    r.u[2] = pack2fast(hi.x, hi.y);
    r.u[3] = pack2fast(hi.z, hi.w);
    return r.v;
}
__device__ __forceinline__ float4 scale4(float4 v, float s) {
    return make_float4(v.x * s, v.y * s, v.z * s, v.w * s);
}
__device__ __forceinline__ float4 relu4(float4 v) {
    return make_float4(fmaxf(v.x, 0.f), fmaxf(v.y, 0.f), fmaxf(v.z, 0.f), fmaxf(v.w, 0.f));
}
__device__ __forceinline__ float2 pkfma(float2 a, float2 b, float2 c) {
    return make_float2(fmaf(a.x, b.x, c.x), fmaf(a.y, b.y, c.y));
}
__device__ __forceinline__ float2 pkmul(float2 a, float2 b) {
    return make_float2(a.x * b.x, a.y * b.y);
}
__device__ __forceinline__ float tanh_c(float c) {
    return fmaf(2.0f, __builtin_amdgcn_rcpf(
        1.0f + __builtin_amdgcn_exp2f(-2.0f * LOG2E * c)), -1.0f);
}
__device__ __forceinline__ float fsigm(float x) {
    return __builtin_amdgcn_rcpf(1.0f + __builtin_amdgcn_exp2f(-LOG2E * x));
}

// Three-wave producer/consumer, PER-WAVE REGISTER SCOPING (v10 fix): each
// wave's weight setup + full loop live inside its own wave-uniform branch so
// the allocator overlays the three live sets (wave0 ~40, wave1 ~35, wave2 ~70
// regs) and fits the 85-VGPR budget for 6 waves/SIMD without spilling.
// All waves execute exactly NB+1 __syncthreads (s_barrier is wave-counted).
//   Wave0: LSTM1 recurrence (butterfly dot, broadcast b128 h-gather).
//   Wave1: LSTM2 scan of chunk c-1 (gates via K-padded MFMA) + FC/store.
//   Wave2: x prefetch + MFMA xg staging for chunk c+1 (double-buffered).
__global__ __launch_bounds__(192, 6)
void lstm_fused_v11(const float* __restrict__ x,
        const float* __restrict__ Wih1, const float* __restrict__ Whh1,
        const float* __restrict__ bih1, const float* __restrict__ bhh1,
        const float* __restrict__ Wih2, const float* __restrict__ Whh2,
        const float* __restrict__ bih2, const float* __restrict__ bhh2,
        const float* __restrict__ Wfc,  const float* __restrict__ bfc,
        float* __restrict__ out)
{
    __shared__ __align__(16) float xgl[2][TB * XSTR];   // xg double buffer
    __shared__ __align__(16) float h1l[2][TB][16];      // h1 chunk ring
    __shared__ __align__(16) float xg2l[TB * 16];       // LSTM2 gate preacts

    const int tid = threadIdx.x;
    const int wid = tid >> 6;
    const int lane = tid & 63;
    const size_t b = blockIdx.x;
    const int tl = lane & 15;
    const int kh = lane >> 4;

    if (wid == 0) {
        // ================= Wave0: LSTM1 recurrence =================
        const int T1 = lane & 3;
        const int j1 = lane >> 2;
        const float aA1 = (T1 == 2) ? 2.0f : 1.0f, aB1 = (T1 == 2) ? -1.0f : 0.0f;
        const int gidx = T1 * 16 + j1;

        float2 wrA0, wrA1, wrB0, wrB1, wrC0, wrC1, wrD0, wrD1;
        {
            const float sA = (T1 == 2) ? 2.0f * LOG2E : LOG2E;
            const float sB = ((T1 ^ 2) == 2) ? 2.0f * LOG2E : LOG2E;
            const float sC = ((T1 ^ 1) == 2) ? 2.0f * LOG2E : LOG2E;
            const float sD = ((T1 ^ 3) == 2) ? 2.0f * LOG2E : LOG2E;
            const float4 wa  = scale4(*(const float4*)(Whh1 + ((T1    ) * 16 + j1) * 16 + 4 * T1), sA);
            const float4 wbv = scale4(*(const float4*)(Whh1 + ((T1 ^ 2) * 16 + j1) * 16 + 4 * T1), sB);
            const float4 wc  = scale4(*(const float4*)(Whh1 + ((T1 ^ 1) * 16 + j1) * 16 + 4 * T1), sC);
            const float4 wd  = scale4(*(const float4*)(Whh1 + ((T1 ^ 3) * 16 + j1) * 16 + 4 * T1), sD);
            wrA0 = make_float2(wa.x, wa.y);   wrA1 = make_float2(wa.z, wa.w);
            wrB0 = make_float2(wbv.x, wbv.y); wrB1 = make_float2(wbv.z, wbv.w);
            wrC0 = make_float2(wc.x, wc.y);   wrC1 = make_float2(wc.z, wc.w);
            wrD0 = make_float2(wd.x, wd.y);   wrD1 = make_float2(wd.z, wd.w);
        }
        if (T1 == 0) h1l[1][15][j1] = 0.f;   // h(-1) = 0
        float c1r = 0.f, h1r = 0.f;
        __syncthreads();

        for (int c = 0; c < NB; ++c) {
            const float* xrow = &xgl[c & 1][0];
            const int rg = c & 1;
            const float* hprev0 = &h1l[rg ^ 1][15][0];
#pragma unroll
            for (int tt = 0; tt < TB; ++tt) {
                const float* hp = (tt == 0) ? hprev0 : &h1l[rg][tt - 1][0];
                const float4 gq = *(const float4*)(hp + 4 * T1);
                const float2 g01 = make_float2(gq.x, gq.y);
                const float2 g23 = make_float2(gq.z, gq.w);
                float2 aA = pkmul(wrA0, g01); aA = pkfma(wrA1, g23, aA);
                float2 aB = pkmul(wrB0, g01); aB = pkfma(wrB1, g23, aB);
                float2 aC = pkmul(wrC0, g01); aC = pkfma(wrC1, g23, aC);
                float2 aD = pkmul(wrD0, g01); aD = pkfma(wrD1, g23, aD);
                const float sA = aA.x + aA.y, sB2 = aB.x + aB.y;
                const float sC = aC.x + aC.y, sD = aD.x + aD.y;
                const float u0 = sA + DPPF(sC, 0xB1);
                const float u1 = sB2 + DPPF(sD, 0xB1);
                const float pre = u0 + DPPF(u1, 0x4E) + xrow[tt * XSTR + gidx];
                const float s1 = __builtin_amdgcn_rcpf(1.0f + __builtin_amdgcn_exp2f(-pre));
                const float act = fmaf(aA1, s1, aB1);
                const float fv = DPPF(act, 0x55);
                const float gv = DPPF(act, 0xAA);
                const float ov = DPPF(act, 0xFF);
                c1r = fmaf(fv, c1r, act * gv);       // valid on T1==0 (act = i)
                h1r = ov * tanh_c(c1r);              // valid on T1==0
                if (T1 == 0) h1l[rg][tt][j1] = h1r;
            }
            __syncthreads();
        }
    } else if (wid == 1) {
        // ================= Wave1: LSTM2 scan + FC =================
        const int m2 = lane >> 4;
        const int T2 = (lane >> 2) & 3;
        const int s2 = lane & 3;
        const int row2 = T2 * 4 + m2;
        const float sc2 = (T2 == 2) ? 2.0f * LOG2E : LOG2E;
        const float aA2 = (T2 == 2) ? 2.0f : 1.0f, aB2 = (T2 == 2) ? -1.0f : 0.0f;
        const float w2h = Whh2[row2 * 4 + s2] * sc2;
        const int ahs = s2 << 6;

        bf16x8 wA2;
        {
            union { unsigned u[4]; bf16x8 v; } z;
            z.u[0] = z.u[1] = z.u[2] = z.u[3] = 0u;
            wA2 = z.v;
            if (kh < 2) {
                const float scr = ((tl >> 2) == 2) ? 2.0f * LOG2E : LOG2E;
                const float* wp = Wih2 + tl * 16 + kh * 8;
                wA2 = make_frag(scale4(*(const float4*)wp, scr),
                                scale4(*(const float4*)(wp + 4), scr));
            }
        }
        f32x4 bias2v;
#pragma unroll
        for (int r = 0; r < 4; ++r) {
            const int g = 4 * kh + r;
            bias2v[r] = (bih2[g] + bhh2[g]) * (((g >> 2) == 2) ? 2.0f * LOG2E : LOG2E);
        }
        const float4 wfc = *(const float4*)(Wfc + lane * 4);
        const float bfcv = bfc[lane];
        float c2r = 0.f, h2v = 0.f, h2s = 0.f;
        __syncthreads();

#define GATES2(RG) do { \
    bf16x8 _bf; \
    { union { unsigned u[4]; bf16x8 v; } _z; _z.u[0]=_z.u[1]=_z.u[2]=_z.u[3]=0u; _bf = _z.v; } \
    if (kh < 2) { \
        const float4 _h0 = *(const float4*)&h1l[RG][tl][8 * kh]; \
        const float4 _h1 = *(const float4*)&h1l[RG][tl][8 * kh + 4]; \
        _bf = make_frag(relu4(_h0), relu4(_h1)); \
    } \
    f32x4 _acc = bias2v; \
    _acc = __builtin_amdgcn_mfma_f32_16x16x32_bf16(wA2, _bf, _acc, 0, 0, 0); \
    _Pragma("unroll") \
    for (int _r = 0; _r < 4; ++_r) \
        xg2l[tl * 16 + 4 * kh + _r] = _acc[_r]; \
} while (0)

#define LSTM2_STEP(TT) do { \
    const float _xg2 = xg2l[(TT) * 16 + row2]; \
    float _p2 = w2h * h2s; \
    _p2 += DPPF(_p2, 0xB1); \
    _p2 += DPPF(_p2, 0x4E); \
    _p2 += _xg2; \
    const float _act2 = fmaf(aA2, \
        __builtin_amdgcn_rcpf(1.0f + __builtin_amdgcn_exp2f(-_p2)), aB2); \
    const float _fv2 = SWZF(_act2, 0x101F); \
    const float _gv2 = SWZF(_act2, 0x201F); \
    const float _ov2 = SWZF(_act2, 0x301F); \
    c2r = fmaf(_fv2, c2r, _act2 * _gv2);     /* valid on T2==0 */ \
    h2v = _ov2 * tanh_c(c2r); \
    h2s = BPERM(ahs, h2v); \
} while (0)

        for (int c = 0; c < NB; ++c) {
            if (c >= 1) {
                GATES2((c - 1) & 1);
#pragma unroll
                for (int tt = 0; tt < TB; ++tt)
                    LSTM2_STEP(tt);
            }
            __syncthreads();
        }
        // tail: LSTM2 chunk NB-1, then FC + sigmoid
        GATES2((NB - 1) & 1);
#pragma unroll
        for (int tt = 0; tt < TB; ++tt)
            LSTM2_STEP(tt);

        const float hq0 = __shfl(h2v, 0);    // h2[m] valid on lanes 16m (T2==0)
        const float hq1 = __shfl(h2v, 16);
        const float hq2 = __shfl(h2v, 32);
        const float hq3 = __shfl(h2v, 48);
        float accf = bfcv;
        accf = fmaf(wfc.x, hq0, accf);
        accf = fmaf(wfc.y, hq1, accf);
        accf = fmaf(wfc.z, hq2, accf);
        accf = fmaf(wfc.w, hq3, accf);
        out[b * 64 + lane] = fsigm(accf);
#undef GATES2
#undef LSTM2_STEP
    } else {
        // ================= Wave2: x prefetch + xg MFMA staging =================
        bf16x8 wb[4][2];
        float bias1[4];
#pragma unroll
        for (int n = 0; n < 4; ++n) {
            const float scn = (n == 2) ? 2.0f * LOG2E : LOG2E;
#pragma unroll
            for (int kk = 0; kk < 2; ++kk) {
                const float* wp = Wih1 + (size_t)(n * 16 + tl) * 64 + kk * 32 + kh * 8;
                wb[n][kk] = make_frag(scale4(*(const float4*)wp, scn),
                                      scale4(*(const float4*)(wp + 4), scn));
            }
            bias1[n] = (bih1[n * 16 + tl] + bhh1[n * 16 + tl]) * scn;
        }
        const float* xb = x + b * (size_t)(T_ALL * 64);
        float4 xpf[4];

#define LOADX(CH) do { \
    const float* _src = xb + (size_t)(CH) * (TB * 64); \
    _Pragma("unroll") \
    for (int _kk = 0; _kk < 2; ++_kk) \
        _Pragma("unroll") \
        for (int _hf = 0; _hf < 2; ++_hf) \
            xpf[_kk * 2 + _hf] = *(const float4*)(_src + tl * 64 + _kk * 32 + kh * 8 + _hf * 4); \
} while (0)

#define MFMA_XG(BUF) do { \
    bf16x8 _a0 = make_frag(xpf[0], xpf[1]); \
    bf16x8 _a1 = make_frag(xpf[2], xpf[3]); \
    _Pragma("unroll") \
    for (int _n = 0; _n < 4; ++_n) { \
        f32x4 _acc = {bias1[_n], bias1[_n], bias1[_n], bias1[_n]}; \
        _acc = __builtin_amdgcn_mfma_f32_16x16x32_bf16(_a0, wb[_n][0], _acc, 0, 0, 0); \
        _acc = __builtin_amdgcn_mfma_f32_16x16x32_bf16(_a1, wb[_n][1], _acc, 0, 0, 0); \
        _Pragma("unroll") \
        for (int _r = 0; _r < 4; ++_r) \
            xgl[BUF][(kh * 4 + _r) * XSTR + _n * 16 + tl] = _acc[_r]; \
    } \
} while (0)

        LOADX(0);
        MFMA_XG(0);
        LOADX(1);
        __syncthreads();

        for (int c = 0; c < NB; ++c) {
            if (c + 1 < NB) {
                bf16x8 a0s = make_frag(xpf[0], xpf[1]);
                bf16x8 a1s = make_frag(xpf[2], xpf[3]);
                if (c + 2 < NB) LOADX(c + 2);
#pragma unroll
                for (int n = 0; n < 4; ++n) {
                    f32x4 acc = {bias1[n], bias1[n], bias1[n], bias1[n]};
                    acc = __builtin_amdgcn_mfma_f32_16x16x32_bf16(a0s, wb[n][0], acc, 0, 0, 0);
                    acc = __builtin_amdgcn_mfma_f32_16x16x32_bf16(a1s, wb[n][1], acc, 0, 0, 0);
#pragma unroll
                    for (int r = 0; r < 4; ++r)
                        xgl[(c + 1) & 1][(kh * 4 + r) * XSTR + n * 16 + tl] = acc[r];
                }
            }
            __syncthreads();
        }
#undef LOADX
#undef MFMA_XG
    }
}

extern "C" void kernel_launch(void* const* d_in, const int* in_sizes, int n_in,
                              void* d_out, int out_size, void* d_ws, size_t ws_size,
                              hipStream_t stream) {
    const float* x    = (const float*)d_in[0];
    const float* Wih1 = (const float*)d_in[1];
    const float* Whh1 = (const float*)d_in[2];
    const float* bih1 = (const float*)d_in[3];
    const float* bhh1 = (const float*)d_in[4];
    const float* Wih2 = (const float*)d_in[5];
    const float* Whh2 = (const float*)d_in[6];
    const float* bih2 = (const float*)d_in[7];
    const float* bhh2 = (const float*)d_in[8];
    const float* Wfc  = (const float*)d_in[9];
    const float* bfc  = (const float*)d_in[10];
    float* out = (float*)d_out;

    lstm_fused_v11<<<dim3(2048), dim3(192), 0, stream>>>(
        x, Wih1, Whh1, bih1, bhh1, Wih2, Whh2, bih2, bhh2, Wfc, bfc, out);
}